// Round 10
// baseline (327.366 us; speedup 1.0000x reference)
//
#include <hip/hip_runtime.h>
#include <hip/hip_bf16.h>
#include <cstdint>

#define B_SZ 16
#define C_IN 512
#define C8   64
#define NSP  4096   // H*W
#define QR   192    // q,k,v stacked rows

typedef __attribute__((ext_vector_type(8))) short s8v;   // 8 bf16 (4 VGPRs)
typedef __attribute__((ext_vector_type(4))) float f4v;   // MFMA acc

// split fp32 -> truncated bf16 hi + bf16(residual). |x - hi - lo| <= ~2^-16 |x|
__device__ __forceinline__ void split_bf16(float x, unsigned short& h, unsigned short& l) {
    unsigned int u = __float_as_uint(x);
    h = (unsigned short)(u >> 16);
    float r = x - __uint_as_float(u & 0xffff0000u);
    l = (unsigned short)(__float_as_uint(r) >> 16);
}

__device__ __forceinline__ void split8(const float* v, s8v& h, s8v& l) {
#pragma unroll
    for (int j = 0; j < 8; ++j) {
        unsigned short hh, ll;
        split_bf16(v[j], hh, ll);
        h[j] = (short)hh; l[j] = (short)ll;
    }
}

// swizzled address into the fp32 [128][128] epilogue LDS (floats).
__device__ __forceinline__ int eqaddr(int row, int n) {
    return row * 128 + ((((n >> 2) ^ ((row & 7) << 2)) << 2) | (n & 3));
}

// ---------------------------------------------------------------------------
// W pre-convert: stacked [192][512] -> whi/wlo bf16 (ushort). ~5 us.
// Keeps the per-iter split8 VALU OUT of k_qkv_en's hot loop (round-9 lesson).
// ---------------------------------------------------------------------------
__global__ __launch_bounds__(256) void k_convW(
    const float* __restrict__ Wq, const float* __restrict__ Wk,
    const float* __restrict__ Wv,
    unsigned short* __restrict__ whi, unsigned short* __restrict__ wlo)
{
    const int o = blockIdx.x;
    const float* src = (o < 64)  ? (Wq + (size_t)o * C_IN)
                     : (o < 128) ? (Wk + (size_t)(o - 64) * C_IN)
                                 : (Wv + (size_t)(o - 128) * C_IN);
    for (int c = threadIdx.x; c < C_IN; c += 256) {
        unsigned short h, l;
        split_bf16(src[c], h, l);
        whi[(size_t)o * C_IN + c] = h;
        wlo[(size_t)o * C_IN + c] = l;
    }
}

// ---------------------------------------------------------------------------
// K1: fused QKV projection + partial energy (round-6 measured version:
// pre-split W staged via b128 loads, no W VALU in hot loop).
// grid (32, B), 512 thr = 8 waves (4M x 2N). Block tile 192x128, BK=32.
// ---------------------------------------------------------------------------
__global__ __launch_bounds__(512, 4) void k_qkv_en(
    const float* __restrict__ x,
    const unsigned short* __restrict__ whi, const unsigned short* __restrict__ wlo,
    const float* __restrict__ bq, const float* __restrict__ bk,
    const float* __restrict__ bv,
    float* __restrict__ v, float* __restrict__ part)
{
    __shared__ __align__(16) unsigned char smem[65536];
    unsigned short* as_h = (unsigned short*)smem;          // [QR*32]
    unsigned short* as_l = as_h + QR * 32;
    unsigned short* xs_h = as_l + QR * 32;                 // [128*32]
    unsigned short* xs_l = xs_h + 128 * 32;
    float* eq = (float*)smem;                              // [128*128] (epilogue)

    const int b  = blockIdx.y;
    const int s  = blockIdx.x;
    const int n0 = s * 128;
    const int t  = threadIdx.x;
    const int w  = t >> 6, l = t & 63;
    const int wm = w >> 1, wn = w & 1;
    const int lm = l & 15, lq = l >> 4;
    const int slot = ((lq ^ (l & 3)) << 3);

    const int nB = t & 127, kgB = t >> 7;
    const int slotB = ((kgB ^ (nB & 3)) << 3);

    const int mW = t >> 2, kgW = t & 3;                    // W staging item 0
    const int dstW0 = mW * 32 + ((kgW ^ (mW & 3)) << 3);   // item 1: +4096
    const size_t sW0 = (size_t)mW * C_IN + kgW * 8;        // item 1: +65536

    f4v acc[3][4];
#pragma unroll
    for (int i = 0; i < 3; ++i)
#pragma unroll
        for (int j = 0; j < 4; ++j) acc[i][j] = (f4v)0.f;

    const float* xcol = x + (size_t)b * C_IN * NSP + n0 + nB;
    float xr[8];
    auto loadB = [&](int K0) {
        const float* s_ = xcol + (size_t)(K0 + kgB * 8) * NSP;
#pragma unroll
        for (int j = 0; j < 8; ++j) xr[j] = s_[(size_t)j * NSP];
    };
    loadB(0);

    for (int it = 0; it < 16; ++it) {
        const int k0 = it * 32;
        __syncthreads();
        // split current x chunk (regs) BEFORE prefetch clobbers xr
        s8v hv, lv;
        {
            unsigned short h, lo_;
#pragma unroll
            for (int j = 0; j < 8; ++j) {
                split_bf16(xr[j], h, lo_);
                hv[j] = (short)h; lv[j] = (short)lo_;
            }
        }
        if (it < 15) loadB(k0 + 32);         // next x: latency spans compute
        // W loads (pre-split, L2-hot) -> regs; latency hides under LDS writes
        s8v wh0 = *(const s8v*)&whi[sW0 + k0];
        s8v wl0 = *(const s8v*)&wlo[sW0 + k0];
        s8v wh1, wl1;
        if (t < 256) {
            wh1 = *(const s8v*)&whi[sW0 + 65536 + k0];
            wl1 = *(const s8v*)&wlo[sW0 + 65536 + k0];
        }
        *(s8v*)&xs_h[nB * 32 + slotB] = hv;
        *(s8v*)&xs_l[nB * 32 + slotB] = lv;
        *(s8v*)&as_h[dstW0] = wh0;
        *(s8v*)&as_l[dstW0] = wl0;
        if (t < 256) {
            *(s8v*)&as_h[dstW0 + 4096] = wh1;
            *(s8v*)&as_l[dstW0 + 4096] = wl1;
        }
        __syncthreads();
        s8v ah[3], al[3], bh[4], bl[4];
#pragma unroll
        for (int fm = 0; fm < 3; ++fm) {
            const int m = wm * 48 + fm * 16 + lm;
            ah[fm] = *(const s8v*)&as_h[m * 32 + slot];
            al[fm] = *(const s8v*)&as_l[m * 32 + slot];
        }
#pragma unroll
        for (int fn = 0; fn < 4; ++fn) {
            const int n = wn * 64 + fn * 16 + lm;
            bh[fn] = *(const s8v*)&xs_h[n * 32 + slot];
            bl[fn] = *(const s8v*)&xs_l[n * 32 + slot];
        }
#pragma unroll
        for (int fm = 0; fm < 3; ++fm)
#pragma unroll
            for (int fn = 0; fn < 4; ++fn) {
                acc[fm][fn] = __builtin_amdgcn_mfma_f32_16x16x32_bf16(
                    ah[fm], bh[fn], acc[fm][fn], 0, 0, 0);
                acc[fm][fn] = __builtin_amdgcn_mfma_f32_16x16x32_bf16(
                    ah[fm], bl[fn], acc[fm][fn], 0, 0, 0);
                acc[fm][fn] = __builtin_amdgcn_mfma_f32_16x16x32_bf16(
                    al[fm], bh[fn], acc[fm][fn], 0, 0, 0);
            }
    }

    // ================= epilogue =================
    __syncthreads();   // all frag reads of staging LDS done; repurpose as eq
#pragma unroll
    for (int fm = 0; fm < 3; ++fm) {
        const int row0f = wm * 48 + fm * 16;   // 16-row segment, class-uniform
        const int rbase = row0f + lq * 4;
        if (row0f >= 128) {
#pragma unroll
            for (int fn = 0; fn < 4; ++fn) {
                const int n = wn * 64 + fn * 16 + lm;
                float* dst = v + ((size_t)b * 64 + (rbase - 128)) * NSP + n0 + n;
#pragma unroll
                for (int r = 0; r < 4; ++r)
                    dst[(size_t)r * NSP] = acc[fm][fn][r] + bv[rbase - 128 + r];
            }
        } else {
            const float* barr = (row0f < 64) ? bq : bk;
            const int boff = rbase & 63;
#pragma unroll
            for (int fn = 0; fn < 4; ++fn) {
                const int n = wn * 64 + fn * 16 + lm;
#pragma unroll
                for (int r = 0; r < 4; ++r)
                    eq[eqaddr(rbase + r, n)] = acc[fm][fn][r] + barr[boff + r];
            }
        }
    }
    __syncthreads();

    // QK^T: wave w -> fc = w>>1, fd = (w&1)*2+{0,1}
    const int fc = w >> 1, fd0 = (w & 1) * 2;
    f4v e0 = (f4v)0.f, e1 = (f4v)0.f;
#pragma unroll
    for (int ks = 0; ks < 4; ++ks) {
        const int nf = ks * 32 + lq * 8;
        float qa[8];
        {
            const int a0 = eqaddr(fc * 16 + lm, nf);
            *(float4*)&qa[0] = *(const float4*)&eq[a0];
            *(float4*)&qa[4] = *(const float4*)&eq[a0 + 4];
        }
        s8v qh, ql_;
        split8(qa, qh, ql_);
        float ka[8];
        {
            const int a0 = eqaddr(64 + fd0 * 16 + lm, nf);
            *(float4*)&ka[0] = *(const float4*)&eq[a0];
            *(float4*)&ka[4] = *(const float4*)&eq[a0 + 4];
        }
        s8v kh, kl_;
        split8(ka, kh, kl_);
        e0 = __builtin_amdgcn_mfma_f32_16x16x32_bf16(qh, kh,  e0, 0, 0, 0);
        e0 = __builtin_amdgcn_mfma_f32_16x16x32_bf16(qh, kl_, e0, 0, 0, 0);
        e0 = __builtin_amdgcn_mfma_f32_16x16x32_bf16(ql_, kh, e0, 0, 0, 0);
        {
            const int a0 = eqaddr(64 + (fd0 + 1) * 16 + lm, nf);
            *(float4*)&ka[0] = *(const float4*)&eq[a0];
            *(float4*)&ka[4] = *(const float4*)&eq[a0 + 4];
        }
        split8(ka, kh, kl_);
        e1 = __builtin_amdgcn_mfma_f32_16x16x32_bf16(qh, kh,  e1, 0, 0, 0);
        e1 = __builtin_amdgcn_mfma_f32_16x16x32_bf16(qh, kl_, e1, 0, 0, 0);
        e1 = __builtin_amdgcn_mfma_f32_16x16x32_bf16(ql_, kh, e1, 0, 0, 0);
    }
    float* pb = part + ((size_t)b * 32 + s) * 4096;
#pragma unroll
    for (int r = 0; r < 4; ++r) {
        const int c = fc * 16 + lq * 4 + r;
        pb[c * 64 + fd0 * 16 + lm]        = e0[r];
        pb[c * 64 + (fd0 + 1) * 16 + lm]  = e1[r];
    }
}

// ---------------------------------------------------------------------------
// K2: fused {reduce partials -> softmax -> M = Wo @ attn -> pre-split store}.
// grid (8, B), 256 thr.
// ---------------------------------------------------------------------------
__global__ __launch_bounds__(256) void k_sm_wo(
    const float* __restrict__ part, const float* __restrict__ Wo,
    unsigned short* __restrict__ mhi, unsigned short* __restrict__ mlo)
{
    __shared__ float es[64][65];     // energy -> attn (in-place)
    __shared__ float wosT[64][68];   // [c][o_local]
    const int b  = blockIdx.y;
    const int o0 = blockIdx.x * 64;
    const int t  = threadIdx.x;
    const int td = t & 15, to = t >> 4;

    // stage Wo^T for this block's o-rows
#pragma unroll
    for (int i = 0; i < 4; ++i) {
        int idx = t + 256 * i;
        int r = idx >> 4, q4 = idx & 15;
        float4 wv = *reinterpret_cast<const float4*>(
            Wo + (size_t)(o0 + r) * 64 + q4 * 4);
        wosT[q4 * 4 + 0][r] = wv.x; wosT[q4 * 4 + 1][r] = wv.y;
        wosT[q4 * 4 + 2][r] = wv.z; wosT[q4 * 4 + 3][r] = wv.w;
    }

    // reduce 32 partial chunks -> es
    const float* p = part + (size_t)b * 32 * 4096;
#pragma unroll
    for (int i = 0; i < 16; ++i) {
        int idx = t + 256 * i;   // 0..4095
        float sum = 0.f;
#pragma unroll 8
        for (int s = 0; s < 32; ++s) sum += p[(size_t)s * 4096 + idx];
        es[idx >> 6][idx & 63] = sum;
    }
    __syncthreads();

    // wave-parallel softmax, in place: wave g handles rows g, g+4, ...
    {
        const int g = t >> 6, d = t & 63;
#pragma unroll
        for (int j = 0; j < 16; ++j) {
            const int r = g + 4 * j;
            float vv = es[r][d];
            float m = vv;
#pragma unroll
            for (int off = 32; off; off >>= 1) m = fmaxf(m, __shfl_xor(m, off));
            float e = __expf(vv - m);
            float sum = e;
#pragma unroll
            for (int off = 32; off; off >>= 1) sum += __shfl_xor(sum, off);
            es[r][d] = e / sum;
        }
    }
    __syncthreads();

    // M tile: 64 o-rows x 64 d, K = 64 (fp32 VALU, tiny)
    float acc[4][4];
#pragma unroll
    for (int i = 0; i < 4; ++i)
#pragma unroll
        for (int j = 0; j < 4; ++j) acc[i][j] = 0.f;
#pragma unroll 8
    for (int kk = 0; kk < 64; ++kk) {
        float4 wv = *reinterpret_cast<const float4*>(&wosT[kk][to * 4]);
        float4 av = *reinterpret_cast<const float4*>(&es[kk][td * 4]);
        const float wr[4] = {wv.x, wv.y, wv.z, wv.w};
        const float ar[4] = {av.x, av.y, av.z, av.w};
#pragma unroll
        for (int i = 0; i < 4; ++i)
#pragma unroll
            for (int j = 0; j < 4; ++j)
                acc[i][j] = fmaf(wr[i], ar[j], acc[i][j]);
    }
#pragma unroll
    for (int i = 0; i < 4; ++i) {
        unsigned short h[4], lo4[4];
#pragma unroll
        for (int j = 0; j < 4; ++j) split_bf16(acc[i][j], h[j], lo4[j]);
        const size_t base = ((size_t)b * 512 + o0 + to * 4 + i) * 64 + td * 4;
        uint2 hp, lp;
        hp.x = (unsigned)h[0]   | ((unsigned)h[1]   << 16);
        hp.y = (unsigned)h[2]   | ((unsigned)h[3]   << 16);
        lp.x = (unsigned)lo4[0] | ((unsigned)lo4[1] << 16);
        lp.y = (unsigned)lo4[2] | ((unsigned)lo4[3] << 16);
        *reinterpret_cast<uint2*>(&mhi[base]) = hp;
        *reinterpret_cast<uint2*>(&mlo[base]) = lp;
    }
}

// ---------------------------------------------------------------------------
// K3: out = M @ v + bo. grid (64, B), 512 thr = 8 waves; v read once.
// ---------------------------------------------------------------------------
__global__ __launch_bounds__(512, 2) void k_out2(
    const float* __restrict__ v,
    const unsigned short* __restrict__ mhi, const unsigned short* __restrict__ mlo,
    const float* __restrict__ bo, float* __restrict__ out)
{
    __shared__ unsigned short vsT_h[64 * 64];   // [n][d], swizzled
    __shared__ unsigned short vsT_l[64 * 64];
    const int b  = blockIdx.y;
    const int n0 = blockIdx.x * 64;
    const int t  = threadIdx.x;
    const int w  = t >> 6, l = t & 63;
    const int lm = l & 15, lq = l >> 4;

#pragma unroll
    for (int i = 0; i < 8; ++i) {
        const int d = w * 8 + i;
        const float xv = v[((size_t)b * 64 + d) * NSP + n0 + l];
        unsigned short h, lo_;
        split_bf16(xv, h, lo_);
        const int addr = l * 64 + ((((d >> 3) ^ (l & 7))) << 3) + (d & 7);
        vsT_h[addr] = h;
        vsT_l[addr] = lo_;
    }
    __syncthreads();

    f4v acc[4][4];
#pragma unroll
    for (int i = 0; i < 4; ++i)
#pragma unroll
        for (int j = 0; j < 4; ++j) acc[i][j] = (f4v)0.f;

    const int obase = w * 64;
#pragma unroll
    for (int ks = 0; ks < 2; ++ks) {
        s8v bh[4], bl[4];
#pragma unroll
        for (int fn = 0; fn < 4; ++fn) {
            const int n = fn * 16 + lm;
            const int addr = n * 64 + ((((ks * 4 + lq) ^ (n & 7))) << 3);
            bh[fn] = *(const s8v*)&vsT_h[addr];
            bl[fn] = *(const s8v*)&vsT_l[addr];
        }
#pragma unroll
        for (int fo = 0; fo < 4; ++fo) {
            const int o = obase + fo * 16 + lm;
            const size_t moff = ((size_t)b * 512 + o) * 64 + ks * 32 + lq * 8;
            s8v ah  = *(const s8v*)&mhi[moff];
            s8v al_ = *(const s8v*)&mlo[moff];
#pragma unroll
            for (int fn = 0; fn < 4; ++fn) {
                acc[fo][fn] = __builtin_amdgcn_mfma_f32_16x16x32_bf16(
                    ah, bh[fn], acc[fo][fn], 0, 0, 0);
                acc[fo][fn] = __builtin_amdgcn_mfma_f32_16x16x32_bf16(
                    ah, bl[fn], acc[fo][fn], 0, 0, 0);
                acc[fo][fn] = __builtin_amdgcn_mfma_f32_16x16x32_bf16(
                    al_, bh[fn], acc[fo][fn], 0, 0, 0);
            }
        }
    }

#pragma unroll
    for (int fo = 0; fo < 4; ++fo) {
        const int orow = obase + fo * 16 + lq * 4;
#pragma unroll
        for (int fn = 0; fn < 4; ++fn) {
            const int nc = n0 + fn * 16 + lm;
            float* dst = out + ((size_t)b * 512 + orow) * NSP + nc;
#pragma unroll
            for (int r = 0; r < 4; ++r)
                dst[(size_t)r * NSP] = acc[fo][fn][r] + bo[orow + r];
        }
    }
}

// ---------------------------------------------------------------------------
extern "C" void kernel_launch(void* const* d_in, const int* in_sizes, int n_in,
                              void* d_out, int out_size, void* d_ws, size_t ws_size,
                              hipStream_t stream)
{
    const float* x  = (const float*)d_in[0];
    const float* Wq = (const float*)d_in[1];
    const float* bq = (const float*)d_in[2];
    const float* Wk = (const float*)d_in[3];
    const float* bk = (const float*)d_in[4];
    const float* Wv = (const float*)d_in[5];
    const float* bv = (const float*)d_in[6];
    const float* Wo = (const float*)d_in[7];
    const float* bo = (const float*)d_in[8];
    float* out = (float*)d_out;

    float* ws   = (float*)d_ws;
    float* v    = ws;                                    // [B,64,N]     16.8 MB
    float* part = v    + (size_t)B_SZ * 64 * NSP;        // [B,32,64,64]  8.4 MB
    unsigned short* mhi = (unsigned short*)(part + (size_t)B_SZ * 32 * 64 * 64);
    unsigned short* mlo = mhi + (size_t)B_SZ * 512 * 64; // 1 MiB each
    unsigned short* whi = mlo + (size_t)B_SZ * 512 * 64; // [192][512] 192 KiB
    unsigned short* wlo = whi + (size_t)QR * C_IN;

    k_convW <<<dim3(QR),       256, 0, stream>>>(Wq, Wk, Wv, whi, wlo);
    k_qkv_en<<<dim3(32, B_SZ), 512, 0, stream>>>(x, whi, wlo, bq, bk, bv, v, part);
    k_sm_wo <<<dim3(8, B_SZ),  256, 0, stream>>>(part, Wo, mhi, mlo);
    k_out2  <<<dim3(64, B_SZ), 512, 0, stream>>>(v, mhi, mlo, bo, out);
}

// Round 13
// 283.195 us; speedup vs baseline: 1.1560x; 1.1560x over previous
//
#include <hip/hip_runtime.h>
#include <hip/hip_bf16.h>
#include <cstdint>

#define B_SZ 16
#define C_IN 512
#define C8   64
#define NSP  4096   // H*W
#define QR   192    // q,k,v stacked rows

typedef __attribute__((ext_vector_type(8))) short s8v;   // 8 bf16 (4 VGPRs)
typedef __attribute__((ext_vector_type(4))) float f4v;   // MFMA acc

// split fp32 -> truncated bf16 hi + bf16(residual). |x - hi - lo| <= ~2^-16 |x|
__device__ __forceinline__ void split_bf16(float x, unsigned short& h, unsigned short& l) {
    unsigned int u = __float_as_uint(x);
    h = (unsigned short)(u >> 16);
    float r = x - __uint_as_float(u & 0xffff0000u);
    l = (unsigned short)(__float_as_uint(r) >> 16);
}

__device__ __forceinline__ void split8(const float* v, s8v& h, s8v& l) {
#pragma unroll
    for (int j = 0; j < 8; ++j) {
        unsigned short hh, ll;
        split_bf16(v[j], hh, ll);
        h[j] = (short)hh; l[j] = (short)ll;
    }
}

// swizzled address into the fp32 [128][128] epilogue LDS (floats).
__device__ __forceinline__ int eqaddr(int row, int n) {
    return row * 128 + ((((n >> 2) ^ ((row & 7) << 2)) << 2) | (n & 3));
}

// ---------------------------------------------------------------------------
// W pre-convert: stacked [192][512] -> whi/wlo bf16 (ushort).
// (R9/R10 lesson: per-iter W split8 in the hot loop costs more than this
// extra launch; keep it separate.)
// ---------------------------------------------------------------------------
__global__ __launch_bounds__(256) void k_convW(
    const float* __restrict__ Wq, const float* __restrict__ Wk,
    const float* __restrict__ Wv,
    unsigned short* __restrict__ whi, unsigned short* __restrict__ wlo)
{
    const int o = blockIdx.x;
    const float* src = (o < 64)  ? (Wq + (size_t)o * C_IN)
                     : (o < 128) ? (Wk + (size_t)(o - 64) * C_IN)
                                 : (Wv + (size_t)(o - 128) * C_IN);
    for (int c = threadIdx.x; c < C_IN; c += 256) {
        unsigned short h, l;
        split_bf16(src[c], h, l);
        whi[(size_t)o * C_IN + c] = h;
        wlo[(size_t)o * C_IN + c] = l;
    }
}

// ---------------------------------------------------------------------------
// K1: fused QKV projection + partial energy (R6-measured structure), with
// T14 W-pipelining: W regs for iter it are loaded right after iter it-1's
// publish barrier, so their L2 latency hides under the 36-MFMA phase and the
// staging-phase ds_write never stalls on vmcnt. Bit-identical numerics.
// grid (32, B), 512 thr = 8 waves (4M x 2N). Block tile 192x128, BK=32.
// ---------------------------------------------------------------------------
__global__ __launch_bounds__(512, 4) void k_qkv_en(
    const float* __restrict__ x,
    const unsigned short* __restrict__ whi, const unsigned short* __restrict__ wlo,
    const float* __restrict__ bq, const float* __restrict__ bk,
    const float* __restrict__ bv,
    float* __restrict__ v, float* __restrict__ part)
{
    __shared__ __align__(16) unsigned char smem[65536];
    unsigned short* as_h = (unsigned short*)smem;          // [QR*32]
    unsigned short* as_l = as_h + QR * 32;
    unsigned short* xs_h = as_l + QR * 32;                 // [128*32]
    unsigned short* xs_l = xs_h + 128 * 32;
    float* eq = (float*)smem;                              // [128*128] (epilogue)

    const int b  = blockIdx.y;
    const int s  = blockIdx.x;
    const int n0 = s * 128;
    const int t  = threadIdx.x;
    const int w  = t >> 6, l = t & 63;
    const int wm = w >> 1, wn = w & 1;
    const int lm = l & 15, lq = l >> 4;
    const int slot = ((lq ^ (l & 3)) << 3);

    const int nB = t & 127, kgB = t >> 7;
    const int slotB = ((kgB ^ (nB & 3)) << 3);

    const int mW = t >> 2, kgW = t & 3;                    // W staging item 0
    const int dstW0 = mW * 32 + ((kgW ^ (mW & 3)) << 3);   // item 1: +4096
    const size_t sW0 = (size_t)mW * C_IN + kgW * 8;        // item 1: +65536

    f4v acc[3][4];
#pragma unroll
    for (int i = 0; i < 3; ++i)
#pragma unroll
        for (int j = 0; j < 4; ++j) acc[i][j] = (f4v)0.f;

    const float* xcol = x + (size_t)b * C_IN * NSP + n0 + nB;
    float xr[8];
    auto loadB = [&](int K0) {
        const float* s_ = xcol + (size_t)(K0 + kgB * 8) * NSP;
#pragma unroll
        for (int j = 0; j < 8; ++j) xr[j] = s_[(size_t)j * NSP];
    };
    // W pipeline registers (live across the MFMA phase; +16 VGPR)
    s8v wh0, wl0, wh1, wl1;
    auto loadW = [&](int K0) {
        wh0 = *(const s8v*)&whi[sW0 + K0];
        wl0 = *(const s8v*)&wlo[sW0 + K0];
        if (t < 256) {
            wh1 = *(const s8v*)&whi[sW0 + 65536 + K0];
            wl1 = *(const s8v*)&wlo[sW0 + 65536 + K0];
        }
    };
    loadB(0);
    loadW(0);

    for (int it = 0; it < 16; ++it) {
        const int k0 = it * 32;
        __syncthreads();
        // split current x chunk (regs) BEFORE prefetch clobbers xr
        s8v hv, lv;
        {
            unsigned short h, lo_;
#pragma unroll
            for (int j = 0; j < 8; ++j) {
                split_bf16(xr[j], h, lo_);
                hv[j] = (short)h; lv[j] = (short)lo_;
            }
        }
        if (it < 15) loadB(k0 + 32);         // next x: latency spans compute
        // W regs were loaded one MFMA phase ago -> ds_write without stall
        *(s8v*)&as_h[dstW0] = wh0;
        *(s8v*)&as_l[dstW0] = wl0;
        if (t < 256) {
            *(s8v*)&as_h[dstW0 + 4096] = wh1;
            *(s8v*)&as_l[dstW0 + 4096] = wl1;
        }
        *(s8v*)&xs_h[nB * 32 + slotB] = hv;
        *(s8v*)&xs_l[nB * 32 + slotB] = lv;
        __syncthreads();
        if (it < 15) loadW(k0 + 32);         // next W: latency spans MFMA
        s8v ah[3], al[3], bh[4], bl[4];
#pragma unroll
        for (int fm = 0; fm < 3; ++fm) {
            const int m = wm * 48 + fm * 16 + lm;
            ah[fm] = *(const s8v*)&as_h[m * 32 + slot];
            al[fm] = *(const s8v*)&as_l[m * 32 + slot];
        }
#pragma unroll
        for (int fn = 0; fn < 4; ++fn) {
            const int n = wn * 64 + fn * 16 + lm;
            bh[fn] = *(const s8v*)&xs_h[n * 32 + slot];
            bl[fn] = *(const s8v*)&xs_l[n * 32 + slot];
        }
#pragma unroll
        for (int fm = 0; fm < 3; ++fm)
#pragma unroll
            for (int fn = 0; fn < 4; ++fn) {
                acc[fm][fn] = __builtin_amdgcn_mfma_f32_16x16x32_bf16(
                    ah[fm], bh[fn], acc[fm][fn], 0, 0, 0);
                acc[fm][fn] = __builtin_amdgcn_mfma_f32_16x16x32_bf16(
                    ah[fm], bl[fn], acc[fm][fn], 0, 0, 0);
                acc[fm][fn] = __builtin_amdgcn_mfma_f32_16x16x32_bf16(
                    al[fm], bh[fn], acc[fm][fn], 0, 0, 0);
            }
    }

    // ================= epilogue =================
    __syncthreads();   // all frag reads of staging LDS done; repurpose as eq
#pragma unroll
    for (int fm = 0; fm < 3; ++fm) {
        const int row0f = wm * 48 + fm * 16;   // 16-row segment, class-uniform
        const int rbase = row0f + lq * 4;
        if (row0f >= 128) {
#pragma unroll
            for (int fn = 0; fn < 4; ++fn) {
                const int n = wn * 64 + fn * 16 + lm;
                float* dst = v + ((size_t)b * 64 + (rbase - 128)) * NSP + n0 + n;
#pragma unroll
                for (int r = 0; r < 4; ++r)
                    dst[(size_t)r * NSP] = acc[fm][fn][r] + bv[rbase - 128 + r];
            }
        } else {
            const float* barr = (row0f < 64) ? bq : bk;
            const int boff = rbase & 63;
#pragma unroll
            for (int fn = 0; fn < 4; ++fn) {
                const int n = wn * 64 + fn * 16 + lm;
#pragma unroll
                for (int r = 0; r < 4; ++r)
                    eq[eqaddr(rbase + r, n)] = acc[fm][fn][r] + barr[boff + r];
            }
        }
    }
    __syncthreads();

    // QK^T: wave w -> fc = w>>1, fd = (w&1)*2+{0,1}
    const int fc = w >> 1, fd0 = (w & 1) * 2;
    f4v e0 = (f4v)0.f, e1 = (f4v)0.f;
#pragma unroll
    for (int ks = 0; ks < 4; ++ks) {
        const int nf = ks * 32 + lq * 8;
        float qa[8];
        {
            const int a0 = eqaddr(fc * 16 + lm, nf);
            *(float4*)&qa[0] = *(const float4*)&eq[a0];
            *(float4*)&qa[4] = *(const float4*)&eq[a0 + 4];
        }
        s8v qh, ql_;
        split8(qa, qh, ql_);
        float ka[8];
        {
            const int a0 = eqaddr(64 + fd0 * 16 + lm, nf);
            *(float4*)&ka[0] = *(const float4*)&eq[a0];
            *(float4*)&ka[4] = *(const float4*)&eq[a0 + 4];
        }
        s8v kh, kl_;
        split8(ka, kh, kl_);
        e0 = __builtin_amdgcn_mfma_f32_16x16x32_bf16(qh, kh,  e0, 0, 0, 0);
        e0 = __builtin_amdgcn_mfma_f32_16x16x32_bf16(qh, kl_, e0, 0, 0, 0);
        e0 = __builtin_amdgcn_mfma_f32_16x16x32_bf16(ql_, kh, e0, 0, 0, 0);
        {
            const int a0 = eqaddr(64 + (fd0 + 1) * 16 + lm, nf);
            *(float4*)&ka[0] = *(const float4*)&eq[a0];
            *(float4*)&ka[4] = *(const float4*)&eq[a0 + 4];
        }
        split8(ka, kh, kl_);
        e1 = __builtin_amdgcn_mfma_f32_16x16x32_bf16(qh, kh,  e1, 0, 0, 0);
        e1 = __builtin_amdgcn_mfma_f32_16x16x32_bf16(qh, kl_, e1, 0, 0, 0);
        e1 = __builtin_amdgcn_mfma_f32_16x16x32_bf16(ql_, kh, e1, 0, 0, 0);
    }
    float* pb = part + ((size_t)b * 32 + s) * 4096;
#pragma unroll
    for (int r = 0; r < 4; ++r) {
        const int c = fc * 16 + lq * 4 + r;
        pb[c * 64 + fd0 * 16 + lm]        = e0[r];
        pb[c * 64 + (fd0 + 1) * 16 + lm]  = e1[r];
    }
}

// ---------------------------------------------------------------------------
// K2b: reduce partials + rowwise softmax (R6 version: 1024 blocks, part read
// once — the sm_wo fusion's 128-block serial re-read was the R9/R10 regression).
// ---------------------------------------------------------------------------
__global__ __launch_bounds__(256) void k_softmax(
    const float* __restrict__ part, float* __restrict__ attn)
{
    __shared__ float red[4][64];
    const int cRow = blockIdx.x, b = blockIdx.y;
    const int t = threadIdx.x, d = t & 63, sg = t >> 6;
    const float* p = part + (size_t)b * 32 * 4096 + cRow * 64 + d;
    float s = 0.f;
#pragma unroll
    for (int i = 0; i < 8; ++i) s += p[(size_t)(sg * 8 + i) * 4096];
    red[sg][d] = s;
    __syncthreads();
    if (t < 64) {
        float v = red[0][d] + red[1][d] + red[2][d] + red[3][d];
        float m = v;
#pragma unroll
        for (int off = 32; off; off >>= 1) m = fmaxf(m, __shfl_xor(m, off));
        float e = __expf(v - m);
        float sum = e;
#pragma unroll
        for (int off = 32; off; off >>= 1) sum += __shfl_xor(sum, off);
        attn[((size_t)b * 64 + cRow) * 64 + d] = e / sum;
    }
}

// ---------------------------------------------------------------------------
// K2c: M = Wo @ attn, stored pre-split as bf16 hi/lo (R6 version). grid (8, B).
// ---------------------------------------------------------------------------
__global__ __launch_bounds__(256) void k_woattn(
    const float* __restrict__ Wo, const float* __restrict__ attn,
    unsigned short* __restrict__ mhi, unsigned short* __restrict__ mlo)
{
    __shared__ float wosT[64][68];
    __shared__ float as[64][68];
    const int b  = blockIdx.y;
    const int o0 = blockIdx.x * 64;
    const int t  = threadIdx.x;
    const int td = t & 15, to = t >> 4;
#pragma unroll
    for (int i = 0; i < 4; ++i) {
        int idx = t + 256 * i;
        int r = idx >> 4, q4 = idx & 15;
        float4 w = *reinterpret_cast<const float4*>(
            Wo + (size_t)(o0 + r) * 64 + q4 * 4);
        wosT[q4 * 4 + 0][r] = w.x; wosT[q4 * 4 + 1][r] = w.y;
        wosT[q4 * 4 + 2][r] = w.z; wosT[q4 * 4 + 3][r] = w.w;
        float4 a = *reinterpret_cast<const float4*>(
            attn + ((size_t)b * 64 + r) * 64 + q4 * 4);
        *reinterpret_cast<float4*>(&as[r][q4 * 4]) = a;
    }
    __syncthreads();
    float acc[4][4];
#pragma unroll
    for (int i = 0; i < 4; ++i)
#pragma unroll
        for (int j = 0; j < 4; ++j) acc[i][j] = 0.f;
#pragma unroll 8
    for (int kk = 0; kk < 64; ++kk) {
        float4 wv = *reinterpret_cast<const float4*>(&wosT[kk][to * 4]);
        float4 av = *reinterpret_cast<const float4*>(&as[kk][td * 4]);
        const float wr[4] = {wv.x, wv.y, wv.z, wv.w};
        const float ar[4] = {av.x, av.y, av.z, av.w};
#pragma unroll
        for (int i = 0; i < 4; ++i)
#pragma unroll
            for (int j = 0; j < 4; ++j)
                acc[i][j] = fmaf(wr[i], ar[j], acc[i][j]);
    }
#pragma unroll
    for (int i = 0; i < 4; ++i) {
        unsigned short h[4], lo4[4];
#pragma unroll
        for (int j = 0; j < 4; ++j) split_bf16(acc[i][j], h[j], lo4[j]);
        const size_t base = ((size_t)b * 512 + o0 + to * 4 + i) * 64 + td * 4;
        uint2 hp, lp;
        hp.x = (unsigned)h[0]   | ((unsigned)h[1]   << 16);
        hp.y = (unsigned)h[2]   | ((unsigned)h[3]   << 16);
        lp.x = (unsigned)lo4[0] | ((unsigned)lo4[1] << 16);
        lp.y = (unsigned)lo4[2] | ((unsigned)lo4[3] << 16);
        *reinterpret_cast<uint2*>(&mhi[base]) = hp;
        *reinterpret_cast<uint2*>(&mlo[base]) = lp;
    }
}

// ---------------------------------------------------------------------------
// K3: out = M @ v + bo. grid (64, B), 512 thr = 8 waves; v read once.
// ---------------------------------------------------------------------------
__global__ __launch_bounds__(512, 2) void k_out2(
    const float* __restrict__ v,
    const unsigned short* __restrict__ mhi, const unsigned short* __restrict__ mlo,
    const float* __restrict__ bo, float* __restrict__ out)
{
    __shared__ unsigned short vsT_h[64 * 64];   // [n][d], swizzled
    __shared__ unsigned short vsT_l[64 * 64];
    const int b  = blockIdx.y;
    const int n0 = blockIdx.x * 64;
    const int t  = threadIdx.x;
    const int w  = t >> 6, l = t & 63;
    const int lm = l & 15, lq = l >> 4;

#pragma unroll
    for (int i = 0; i < 8; ++i) {
        const int d = w * 8 + i;
        const float xv = v[((size_t)b * 64 + d) * NSP + n0 + l];
        unsigned short h, lo_;
        split_bf16(xv, h, lo_);
        const int addr = l * 64 + ((((d >> 3) ^ (l & 7))) << 3) + (d & 7);
        vsT_h[addr] = h;
        vsT_l[addr] = lo_;
    }
    __syncthreads();

    f4v acc[4][4];
#pragma unroll
    for (int i = 0; i < 4; ++i)
#pragma unroll
        for (int j = 0; j < 4; ++j) acc[i][j] = (f4v)0.f;

    const int obase = w * 64;
#pragma unroll
    for (int ks = 0; ks < 2; ++ks) {
        s8v bh[4], bl[4];
#pragma unroll
        for (int fn = 0; fn < 4; ++fn) {
            const int n = fn * 16 + lm;
            const int addr = n * 64 + ((((ks * 4 + lq) ^ (n & 7))) << 3);
            bh[fn] = *(const s8v*)&vsT_h[addr];
            bl[fn] = *(const s8v*)&vsT_l[addr];
        }
#pragma unroll
        for (int fo = 0; fo < 4; ++fo) {
            const int o = obase + fo * 16 + lm;
            const size_t moff = ((size_t)b * 512 + o) * 64 + ks * 32 + lq * 8;
            s8v ah  = *(const s8v*)&mhi[moff];
            s8v al_ = *(const s8v*)&mlo[moff];
#pragma unroll
            for (int fn = 0; fn < 4; ++fn) {
                acc[fo][fn] = __builtin_amdgcn_mfma_f32_16x16x32_bf16(
                    ah, bh[fn], acc[fo][fn], 0, 0, 0);
                acc[fo][fn] = __builtin_amdgcn_mfma_f32_16x16x32_bf16(
                    ah, bl[fn], acc[fo][fn], 0, 0, 0);
                acc[fo][fn] = __builtin_amdgcn_mfma_f32_16x16x32_bf16(
                    al_, bh[fn], acc[fo][fn], 0, 0, 0);
            }
        }
    }

#pragma unroll
    for (int fo = 0; fo < 4; ++fo) {
        const int orow = obase + fo * 16 + lq * 4;
#pragma unroll
        for (int fn = 0; fn < 4; ++fn) {
            const int nc = n0 + fn * 16 + lm;
            float* dst = out + ((size_t)b * 512 + orow) * NSP + nc;
#pragma unroll
            for (int r = 0; r < 4; ++r)
                dst[(size_t)r * NSP] = acc[fo][fn][r] + bo[orow + r];
        }
    }
}

// ---------------------------------------------------------------------------
extern "C" void kernel_launch(void* const* d_in, const int* in_sizes, int n_in,
                              void* d_out, int out_size, void* d_ws, size_t ws_size,
                              hipStream_t stream)
{
    const float* x  = (const float*)d_in[0];
    const float* Wq = (const float*)d_in[1];
    const float* bq = (const float*)d_in[2];
    const float* Wk = (const float*)d_in[3];
    const float* bk = (const float*)d_in[4];
    const float* Wv = (const float*)d_in[5];
    const float* bv = (const float*)d_in[6];
    const float* Wo = (const float*)d_in[7];
    const float* bo = (const float*)d_in[8];
    float* out = (float*)d_out;

    float* ws   = (float*)d_ws;
    float* v    = ws;                                    // [B,64,N]     16.8 MB
    float* part = v    + (size_t)B_SZ * 64 * NSP;        // [B,32,64,64]  8.4 MB
    float* attn = part + (size_t)B_SZ * 32 * 64 * 64;    // [B,64,64]   256 KiB
    unsigned short* mhi = (unsigned short*)(attn + (size_t)B_SZ * 64 * 64);
    unsigned short* mlo = mhi + (size_t)B_SZ * 512 * 64; // 1 MiB each
    unsigned short* whi = mlo + (size_t)B_SZ * 512 * 64; // [192][512] 192 KiB
    unsigned short* wlo = whi + (size_t)QR * C_IN;

    k_convW  <<<dim3(QR),       256, 0, stream>>>(Wq, Wk, Wv, whi, wlo);
    k_qkv_en <<<dim3(32, B_SZ), 512, 0, stream>>>(x, whi, wlo, bq, bk, bv, v, part);
    k_softmax<<<dim3(64, B_SZ), 256, 0, stream>>>(part, attn);
    k_woattn <<<dim3(8, B_SZ),  256, 0, stream>>>(Wo, attn, mhi, mlo);
    k_out2   <<<dim3(64, B_SZ), 512, 0, stream>>>(v, mhi, mlo, bo, out);
}